// Round 1
// baseline (12354.369 us; speedup 1.0000x reference)
//
#include <hip/hip_runtime.h>

// KGCN-style propagation:
//   entity_out = mean(emb, S_kg·emb, S_kg²·emb)                      [150000 x 64]
//   ui_emb     = concat(user_emb, entity_out[:50000])                [150000 x 64]
//   user_out   = mean over 4 terms of S_ui^k · ui_emb, user rows     [100000 x 64]
// d_out = [user_out (6.4M floats) | entity_out (9.6M floats)]
//
// ws layout: A (9.6M floats) | B (9.6M floats)  -> needs 76.8 MB.

constexpr int D = 64;

// --- fused elementwise kernels (float4-vectorized) ---

__global__ void init_ent_kernel(const float4* __restrict__ emb, float4* __restrict__ cur,
                                float4* __restrict__ acc, float4* __restrict__ nxt, long n4) {
    long i = (long)blockIdx.x * blockDim.x + threadIdx.x;
    if (i < n4) {
        float4 v = emb[i];
        cur[i] = v;
        acc[i] = v;
        nxt[i] = make_float4(0.f, 0.f, 0.f, 0.f);
    }
}

__global__ void acc_add_zero_kernel(float4* __restrict__ acc, const float4* __restrict__ next,
                                    float4* __restrict__ z, long nAcc4, long nZero4) {
    long i = (long)blockIdx.x * blockDim.x + threadIdx.x;
    if (i < nZero4) {
        if (i < nAcc4) {
            float4 a = acc[i];
            float4 b = next[i];
            a.x += b.x; a.y += b.y; a.z += b.z; a.w += b.w;
            acc[i] = a;
        }
        z[i] = make_float4(0.f, 0.f, 0.f, 0.f);
    }
}

__global__ void acc_final_kernel(float4* __restrict__ acc, const float4* __restrict__ next,
                                 float s, long n4) {
    long i = (long)blockIdx.x * blockDim.x + threadIdx.x;
    if (i < n4) {
        float4 a = acc[i];
        float4 b = next[i];
        a.x = (a.x + b.x) * s; a.y = (a.y + b.y) * s;
        a.z = (a.z + b.z) * s; a.w = (a.w + b.w) * s;
        acc[i] = a;
    }
}

// cur = concat(user_emb, ent_out[:n_items]); dacc(user rows) = user_emb; z = 0
__global__ void build_ui_kernel(const float4* __restrict__ uemb, const float4* __restrict__ eout,
                                float4* __restrict__ cur, float4* __restrict__ dacc,
                                float4* __restrict__ z, long nUser4, long nTot4) {
    long i = (long)blockIdx.x * blockDim.x + threadIdx.x;
    if (i < nTot4) {
        float4 v = (i < nUser4) ? uemb[i] : eout[i - nUser4];
        cur[i] = v;
        if (i < nUser4) dacc[i] = v;
        z[i] = make_float4(0.f, 0.f, 0.f, 0.f);
    }
}

// --- SpMM scatter: next[row[e]] += vals[e] * cur[col[e]]  (16 threads/edge) ---

__global__ void spmm_kernel(const int* __restrict__ row, const int* __restrict__ col,
                            const float* __restrict__ vals, const float* __restrict__ cur,
                            float* __restrict__ next, int nnz) {
    long t = (long)blockIdx.x * blockDim.x + threadIdx.x;
    long e = t >> 4;                 // 16 threads per edge
    if (e >= nnz) return;
    int lane = (int)(t & 15);
    int r = row[e];
    int c = col[e];
    float w = vals[e];
    const float4 v = *reinterpret_cast<const float4*>(cur + (long)c * D + lane * 4);
    float* dst = next + (long)r * D + lane * 4;
    unsafeAtomicAdd(dst + 0, w * v.x);
    unsafeAtomicAdd(dst + 1, w * v.y);
    unsafeAtomicAdd(dst + 2, w * v.z);
    unsafeAtomicAdd(dst + 3, w * v.w);
}

extern "C" void kernel_launch(void* const* d_in, const int* in_sizes, int n_in,
                              void* d_out, int out_size, void* d_ws, size_t ws_size,
                              hipStream_t stream) {
    const float* user_emb   = (const float*)d_in[0];
    const float* entity_emb = (const float*)d_in[1];
    const int*   kg_row     = (const int*)d_in[2];
    const int*   kg_col     = (const int*)d_in[3];
    const float* kg_vals    = (const float*)d_in[4];
    const int*   ui_row     = (const int*)d_in[5];
    const int*   ui_col     = (const int*)d_in[6];
    const float* ui_vals    = (const float*)d_in[7];

    const int n_users    = in_sizes[0] / D;   // 100000
    const int n_entities = in_sizes[1] / D;   // 150000
    const int kg_nnz     = in_sizes[2];       // 2.4M
    const int ui_nnz     = in_sizes[5];       // 3.2M
    const int n_ui       = n_entities;        // 150000 == n_users + n_items for this setup

    const long nEnt4  = (long)n_entities * (D / 4);  // 2.4M float4
    const long nUser4 = (long)n_users    * (D / 4);  // 1.6M float4
    const long nUI4   = (long)n_ui       * (D / 4);  // 2.4M float4

    float* A = (float*)d_ws;
    float* B = A + (long)n_ui * D;                    // 9.6M floats each

    float* dout_user = (float*)d_out;                 // 6.4M floats
    float* dout_ent  = dout_user + (long)n_users * D; // 9.6M floats

    const int BLK = 256;
    const int gE  = (int)((nEnt4 + BLK - 1) / BLK);
    const int gU  = (int)((nUser4 + BLK - 1) / BLK);
    const int gKG = (int)(((long)kg_nnz * 16 + BLK - 1) / BLK);
    const int gUI = (int)(((long)ui_nnz * 16 + BLK - 1) / BLK);

    // ---- entity (KG) phase: 2 layers ----
    // A = emb, acc(d_out ent) = emb, B = 0
    init_ent_kernel<<<gE, BLK, 0, stream>>>((const float4*)entity_emb, (float4*)A,
                                            (float4*)dout_ent, (float4*)B, nEnt4);
    // layer 1: B += S·A
    spmm_kernel<<<gKG, BLK, 0, stream>>>(kg_row, kg_col, kg_vals, A, B, kg_nnz);
    // acc += B; A = 0
    acc_add_zero_kernel<<<gE, BLK, 0, stream>>>((float4*)dout_ent, (const float4*)B,
                                                (float4*)A, nEnt4, nEnt4);
    // layer 2: A += S·B
    spmm_kernel<<<gKG, BLK, 0, stream>>>(kg_row, kg_col, kg_vals, B, A, kg_nnz);
    // acc = (acc + A)/3   -> entity_out done (in d_out)
    acc_final_kernel<<<gE, BLK, 0, stream>>>((float4*)dout_ent, (const float4*)A,
                                             1.0f / 3.0f, nEnt4);

    // ---- UI phase: 3 layers (acc only needed on user rows) ----
    // B = concat(user_emb, entity_out[:n_items]); dout_user = user_emb; A = 0
    build_ui_kernel<<<gE, BLK, 0, stream>>>((const float4*)user_emb, (const float4*)dout_ent,
                                            (float4*)B, (float4*)dout_user, (float4*)A,
                                            nUser4, nUI4);
    // layer 1: A += S·B
    spmm_kernel<<<gUI, BLK, 0, stream>>>(ui_row, ui_col, ui_vals, B, A, ui_nnz);
    acc_add_zero_kernel<<<gE, BLK, 0, stream>>>((float4*)dout_user, (const float4*)A,
                                                (float4*)B, nUser4, nUI4);
    // layer 2: B += S·A
    spmm_kernel<<<gUI, BLK, 0, stream>>>(ui_row, ui_col, ui_vals, A, B, ui_nnz);
    acc_add_zero_kernel<<<gE, BLK, 0, stream>>>((float4*)dout_user, (const float4*)B,
                                                (float4*)A, nUser4, nUI4);
    // layer 3: A += S·B
    spmm_kernel<<<gUI, BLK, 0, stream>>>(ui_row, ui_col, ui_vals, B, A, ui_nnz);
    // user_out = (acc + A[user rows]) / 4
    acc_final_kernel<<<gU, BLK, 0, stream>>>((float4*)dout_user, (const float4*)A,
                                             0.25f, nUser4);
}

// Round 8
// 2028.208 us; speedup vs baseline: 6.0913x; 6.0913x over previous
//
#include <hip/hip_runtime.h>
#include <hip/hip_fp16.h>

// KGCN-style propagation, PULL-based CSR, fp16 inter-layer tables:
//   entity_out = (emb + S_kg·emb + S_kg²·emb) / 3          [150000 x 64]
//   ui_emb     = concat(user_emb, entity_out[:50000])      [150000 x 64]
//   user_out   = (Σ_{k=0..3} S_ui^k·ui_emb)[:100000] / 4   [100000 x 64]
// d_out = [user_out (6.4M f32) | entity_out (9.6M f32)]
// Accumulators (d_out) stay f32; ping-pong tables A/B are __half (19.2 MB each).

constexpr int D = 64;

// ---------------- CSR build (counting sort) ----------------

__global__ void zero_kernel(int* __restrict__ p, int n) {
    int i = blockIdx.x * blockDim.x + threadIdx.x;
    if (i < n) p[i] = 0;
}

__global__ void hist_kernel(const int* __restrict__ row, int* __restrict__ cnt, int nnz) {
    int i = blockIdx.x * blockDim.x + threadIdx.x;
    if (i < nnz) atomicAdd(&cnt[row[i]], 1);
}

// one-block scan: reads cnt, writes rp[0..n], rewrites cnt in place as cursor.
#define SCAN_T 1024
__global__ void scan_kernel(int* __restrict__ cnt, int* __restrict__ rp, int n) {
    __shared__ int lds[SCAN_T];
    int tid = threadIdx.x;
    int chunk = (n + SCAN_T - 1) / SCAN_T;
    int lo = tid * chunk;
    int hi = min(lo + chunk, n);
    int sum = 0;
    for (int i = lo; i < hi; ++i) sum += cnt[i];
    lds[tid] = sum;
    __syncthreads();
    for (int ofs = 1; ofs < SCAN_T; ofs <<= 1) {
        int v = (tid >= ofs) ? lds[tid - ofs] : 0;
        __syncthreads();
        lds[tid] += v;
        __syncthreads();
    }
    int run = (tid > 0) ? lds[tid - 1] : 0;
    for (int i = lo; i < hi; ++i) {
        int c = cnt[i];
        rp[i] = run;
        cnt[i] = run;   // becomes the scatter cursor
        run += c;
    }
    if (tid == SCAN_T - 1) rp[n] = lds[SCAN_T - 1];
}

__global__ void scatter_kernel(const int* __restrict__ row, const int* __restrict__ col,
                               const float* __restrict__ val, int* __restrict__ cursor,
                               int* __restrict__ cs, float* __restrict__ vs, int nnz) {
    int i = blockIdx.x * blockDim.x + threadIdx.x;
    if (i < nnz) {
        int p = atomicAdd(&cursor[row[i]], 1);
        cs[p] = col[i];
        vs[p] = val[i];
    }
}

// ---------------- pull SpMM: one wave per row, lane = dim ----------------
__device__ __forceinline__ float ldval(const float* p) { return *p; }
__device__ __forceinline__ float ldval(const __half* p) { return __half2float(*p); }

// s = Σ_e vs[e] * cur[cs[e]*64 + lane]
// if (next)            next[row] = (half)s
// if (row < acc_rows)  mode 1: acc[row] = cur[row] + s       (acc init, layer 1)
//                      mode 2: acc[row] += s                 (middle layer)
//                      mode 3: acc[row] = (acc[row]+s)*scale (final layer)
template <typename TIn>
__global__ void spmm_csr_kernel(const int* __restrict__ rp, const int* __restrict__ cs,
                                const float* __restrict__ vs, const TIn* __restrict__ cur,
                                __half* __restrict__ next, float* __restrict__ acc,
                                int n_rows, int acc_rows, int mode, float scale) {
    int wid = (int)(((long)blockIdx.x * blockDim.x + threadIdx.x) >> 6);
    int lane = threadIdx.x & 63;
    if (wid >= n_rows) return;
    int start = rp[wid];
    int end = rp[wid + 1];
    float s0 = 0.f, s1 = 0.f, s2 = 0.f, s3 = 0.f;
    int e = start;
    for (; e + 3 < end; e += 4) {
        int c0 = cs[e], c1 = cs[e + 1], c2 = cs[e + 2], c3 = cs[e + 3];
        float w0 = vs[e], w1 = vs[e + 1], w2 = vs[e + 2], w3 = vs[e + 3];
        s0 += w0 * ldval(cur + (long)c0 * D + lane);
        s1 += w1 * ldval(cur + (long)c1 * D + lane);
        s2 += w2 * ldval(cur + (long)c2 * D + lane);
        s3 += w3 * ldval(cur + (long)c3 * D + lane);
    }
    for (; e < end; ++e) s0 += vs[e] * ldval(cur + (long)cs[e] * D + lane);
    float s = (s0 + s1) + (s2 + s3);
    long o = (long)wid * D + lane;
    if (next) next[o] = __float2half(s);
    if (wid < acc_rows) {
        if (mode == 1)      acc[o] = ldval(cur + o) + s;
        else if (mode == 2) acc[o] += s;
        else if (mode == 3) acc[o] = (acc[o] + s) * scale;
    }
}

// dst(half) = concat(user_emb, entity_out[:n_items])  (float4 in, 4x half out)
__global__ void concat_half_kernel(const float4* __restrict__ u, const float4* __restrict__ e,
                                   ushort4* __restrict__ dst, long nU4, long nT4) {
    long i = (long)blockIdx.x * blockDim.x + threadIdx.x;
    if (i < nT4) {
        float4 v = (i < nU4) ? u[i] : e[i - nU4];
        ushort4 h;
        h.x = __half_as_ushort(__float2half(v.x));
        h.y = __half_as_ushort(__float2half(v.y));
        h.z = __half_as_ushort(__float2half(v.z));
        h.w = __half_as_ushort(__float2half(v.w));
        dst[i] = h;
    }
}

extern "C" void kernel_launch(void* const* d_in, const int* in_sizes, int n_in,
                              void* d_out, int out_size, void* d_ws, size_t ws_size,
                              hipStream_t stream) {
    const float* user_emb   = (const float*)d_in[0];
    const float* entity_emb = (const float*)d_in[1];
    const int*   kg_row     = (const int*)d_in[2];
    const int*   kg_col     = (const int*)d_in[3];
    const float* kg_vals    = (const float*)d_in[4];
    const int*   ui_row     = (const int*)d_in[5];
    const int*   ui_col     = (const int*)d_in[6];
    const float* ui_vals    = (const float*)d_in[7];

    const int n_users    = in_sizes[0] / D;   // 100000
    const int n_entities = in_sizes[1] / D;   // 150000
    const int kg_nnz     = in_sizes[2];       // 2.4M
    const int ui_nnz     = in_sizes[5];       // 3.2M
    const int n_ui       = n_entities;        // 150000 = n_users + n_items here

    // ---- ws layout ----
    __half* A = (__half*)d_ws;                     // n_ui*64 halfs (19.2 MB)
    __half* B = A + (long)n_ui * D;                // n_ui*64 halfs
    int*   kg_cnt = (int*)(B + (long)n_ui * D);    // n_entities (hist, then cursor)
    int*   kg_rp  = kg_cnt + n_entities;           // n_entities+1
    int*   kg_cs  = kg_rp + n_entities + 1;        // kg_nnz
    float* kg_vs  = (float*)(kg_cs + kg_nnz);      // kg_nnz
    int*   ui_cnt = (int*)(kg_vs + kg_nnz);        // n_ui (hist, then cursor)
    int*   ui_rp  = ui_cnt + n_ui;                 // n_ui+1
    int*   ui_cs  = ui_rp + n_ui + 1;              // ui_nnz
    float* ui_vs  = (float*)(ui_cs + ui_nnz);      // ui_nnz

    float* dout_user = (float*)d_out;                  // 6.4M floats
    float* dout_ent  = dout_user + (long)n_users * D;  // 9.6M floats

    const int BLK = 256;
    auto cdiv = [](long a, long b) { return (int)((a + b - 1) / b); };

    // ---- build CSR: KG ----
    zero_kernel<<<cdiv(n_entities, BLK), BLK, 0, stream>>>(kg_cnt, n_entities);
    hist_kernel<<<cdiv(kg_nnz, BLK), BLK, 0, stream>>>(kg_row, kg_cnt, kg_nnz);
    scan_kernel<<<1, SCAN_T, 0, stream>>>(kg_cnt, kg_rp, n_entities);
    scatter_kernel<<<cdiv(kg_nnz, BLK), BLK, 0, stream>>>(kg_row, kg_col, kg_vals,
                                                          kg_cnt, kg_cs, kg_vs, kg_nnz);
    // ---- build CSR: UI ----
    zero_kernel<<<cdiv(n_ui, BLK), BLK, 0, stream>>>(ui_cnt, n_ui);
    hist_kernel<<<cdiv(ui_nnz, BLK), BLK, 0, stream>>>(ui_row, ui_cnt, ui_nnz);
    scan_kernel<<<1, SCAN_T, 0, stream>>>(ui_cnt, ui_rp, n_ui);
    scatter_kernel<<<cdiv(ui_nnz, BLK), BLK, 0, stream>>>(ui_row, ui_col, ui_vals,
                                                          ui_cnt, ui_cs, ui_vs, ui_nnz);

    // ---- entity (KG) phase: 2 layers ----
    // l1: A(half) = S·emb ; dout_ent = emb + S·emb   (gather from f32 input)
    spmm_csr_kernel<float><<<cdiv((long)n_entities * 64, BLK), BLK, 0, stream>>>(
        kg_rp, kg_cs, kg_vs, entity_emb, A, dout_ent, n_entities, n_entities, 1, 0.f);
    // l2: dout_ent = (dout_ent + S·A) / 3
    spmm_csr_kernel<__half><<<cdiv((long)n_entities * 64, BLK), BLK, 0, stream>>>(
        kg_rp, kg_cs, kg_vs, A, (__half*)nullptr, dout_ent, n_entities, n_entities, 3, 1.f / 3.f);

    // ---- UI phase: 3 layers ----
    // B(half) = concat(user_emb, entity_out[:n_items])
    concat_half_kernel<<<cdiv((long)n_ui * (D / 4), BLK), BLK, 0, stream>>>(
        (const float4*)user_emb, (const float4*)dout_ent, (ushort4*)B,
        (long)n_users * (D / 4), (long)n_ui * (D / 4));
    // l1: A = S·B ; dout_user = B[:U] + S·B[:U]
    spmm_csr_kernel<__half><<<cdiv((long)n_ui * 64, BLK), BLK, 0, stream>>>(
        ui_rp, ui_cs, ui_vs, B, A, dout_user, n_ui, n_users, 1, 0.f);
    // l2: B = S·A ; dout_user += (S·A)[:U]
    spmm_csr_kernel<__half><<<cdiv((long)n_ui * 64, BLK), BLK, 0, stream>>>(
        ui_rp, ui_cs, ui_vs, A, B, dout_user, n_ui, n_users, 2, 0.f);
    // l3 (user rows only): dout_user = (dout_user + S·B) / 4
    spmm_csr_kernel<__half><<<cdiv((long)n_users * 64, BLK), BLK, 0, stream>>>(
        ui_rp, ui_cs, ui_vs, B, (__half*)nullptr, dout_user, n_users, n_users, 3, 0.25f);
}

// Round 10
// 1394.988 us; speedup vs baseline: 8.8563x; 1.4539x over previous
//
#include <hip/hip_runtime.h>
#include <hip/hip_fp16.h>

// KGCN-style propagation, PULL-based CSR, fp16 inter-layer tables,
// hierarchical parallel scan for CSR row pointers.
//   entity_out = (emb + S_kg·emb + S_kg²·emb) / 3          [150000 x 64]
//   ui_emb     = concat(user_emb, entity_out[:50000])      [150000 x 64]
//   user_out   = (Σ_{k=0..3} S_ui^k·ui_emb)[:100000] / 4   [100000 x 64]
// d_out = [user_out (6.4M f32) | entity_out (9.6M f32)]

constexpr int D = 64;
constexpr int SCAN_BLOCKS = 32;
constexpr int SCAN_BT = 256;
constexpr int SCAN_THREADS = SCAN_BLOCKS * SCAN_BT;   // 8192

// ---------------- CSR build (counting sort) ----------------

__global__ void zero_kernel(int* __restrict__ p, int n) {
    int i = blockIdx.x * blockDim.x + threadIdx.x;
    if (i < n) p[i] = 0;
}

__global__ void hist_kernel(const int* __restrict__ row, int* __restrict__ cnt, int nnz) {
    int i = blockIdx.x * blockDim.x + threadIdx.x;
    if (i < nnz) atomicAdd(&cnt[row[i]], 1);
}

// S1: thread t sums its chunk of cnt -> tsum[t]
__global__ void scan_s1_kernel(const int* __restrict__ cnt, int* __restrict__ tsum, int n) {
    int t = blockIdx.x * blockDim.x + threadIdx.x;
    int chunk = (n + SCAN_THREADS - 1) / SCAN_THREADS;
    int lo = t * chunk;
    int hi = min(lo + chunk, n);
    int s = 0;
    for (int i = lo; i < hi; ++i) s += cnt[i];
    tsum[t] = s;
}

// S2: single block, exclusive scan of tsum[SCAN_THREADS] in place (each thread owns 8)
__global__ void scan_s2_kernel(int* __restrict__ tsum) {
    __shared__ int lds[1024];
    int tid = threadIdx.x;                     // 1024 threads
    const int PER = SCAN_THREADS / 1024;       // 8
    int v[PER];
    int s = 0;
    for (int j = 0; j < PER; ++j) { v[j] = tsum[tid * PER + j]; s += v[j]; }
    lds[tid] = s;
    __syncthreads();
    for (int ofs = 1; ofs < 1024; ofs <<= 1) {
        int x = (tid >= ofs) ? lds[tid - ofs] : 0;
        __syncthreads();
        lds[tid] += x;
        __syncthreads();
    }
    int run = (tid > 0) ? lds[tid - 1] : 0;    // exclusive prefix of this thread's group
    for (int j = 0; j < PER; ++j) { int c = v[j]; tsum[tid * PER + j] = run; run += c; }
}

// S3: thread t re-reads its chunk, emits rp[] and cursor (cnt in place)
__global__ void scan_s3_kernel(int* __restrict__ cnt, const int* __restrict__ tsum,
                               int* __restrict__ rp, int n) {
    int t = blockIdx.x * blockDim.x + threadIdx.x;
    int chunk = (n + SCAN_THREADS - 1) / SCAN_THREADS;
    int lo = t * chunk;
    int hi = min(lo + chunk, n);
    int run = tsum[t];
    for (int i = lo; i < hi; ++i) {
        int c = cnt[i];
        rp[i] = run;
        cnt[i] = run;   // becomes the scatter cursor
        run += c;
    }
    if (hi == n && lo <= n) rp[n] = run;   // last chunk writes total
}

__global__ void scatter_kernel(const int* __restrict__ row, const int* __restrict__ col,
                               const float* __restrict__ val, int* __restrict__ cursor,
                               int* __restrict__ cs, float* __restrict__ vs, int nnz) {
    int i = blockIdx.x * blockDim.x + threadIdx.x;
    if (i < nnz) {
        int p = atomicAdd(&cursor[row[i]], 1);
        cs[p] = col[i];
        vs[p] = val[i];
    }
}

// ---------------- pull SpMM: one wave per row, lane = dim ----------------
__device__ __forceinline__ float ldval(const float* p) { return *p; }
__device__ __forceinline__ float ldval(const __half* p) { return __half2float(*p); }

// s = Σ_e vs[e] * cur[cs[e]*64 + lane]
// if (next)            next[row] = (half)s
// if (row < acc_rows)  mode 1: acc[row] = cur[row] + s
//                      mode 2: acc[row] += s
//                      mode 3: acc[row] = (acc[row]+s)*scale
template <typename TIn>
__global__ void spmm_csr_kernel(const int* __restrict__ rp, const int* __restrict__ cs,
                                const float* __restrict__ vs, const TIn* __restrict__ cur,
                                __half* __restrict__ next, float* __restrict__ acc,
                                int n_rows, int acc_rows, int mode, float scale) {
    int wid = (int)(((long)blockIdx.x * blockDim.x + threadIdx.x) >> 6);
    int lane = threadIdx.x & 63;
    if (wid >= n_rows) return;
    int start = rp[wid];
    int end = rp[wid + 1];
    float s0 = 0.f, s1 = 0.f, s2 = 0.f, s3 = 0.f;
    int e = start;
    for (; e + 3 < end; e += 4) {
        int c0 = cs[e], c1 = cs[e + 1], c2 = cs[e + 2], c3 = cs[e + 3];
        float w0 = vs[e], w1 = vs[e + 1], w2 = vs[e + 2], w3 = vs[e + 3];
        s0 += w0 * ldval(cur + (long)c0 * D + lane);
        s1 += w1 * ldval(cur + (long)c1 * D + lane);
        s2 += w2 * ldval(cur + (long)c2 * D + lane);
        s3 += w3 * ldval(cur + (long)c3 * D + lane);
    }
    for (; e < end; ++e) s0 += vs[e] * ldval(cur + (long)cs[e] * D + lane);
    float s = (s0 + s1) + (s2 + s3);
    long o = (long)wid * D + lane;
    if (next) next[o] = __float2half(s);
    if (wid < acc_rows) {
        if (mode == 1)      acc[o] = ldval(cur + o) + s;
        else if (mode == 2) acc[o] += s;
        else if (mode == 3) acc[o] = (acc[o] + s) * scale;
    }
}

// dst(half) = concat(user_emb, entity_out[:n_items])
__global__ void concat_half_kernel(const float4* __restrict__ u, const float4* __restrict__ e,
                                   ushort4* __restrict__ dst, long nU4, long nT4) {
    long i = (long)blockIdx.x * blockDim.x + threadIdx.x;
    if (i < nT4) {
        float4 v = (i < nU4) ? u[i] : e[i - nU4];
        ushort4 h;
        h.x = __half_as_ushort(__float2half(v.x));
        h.y = __half_as_ushort(__float2half(v.y));
        h.z = __half_as_ushort(__float2half(v.z));
        h.w = __half_as_ushort(__float2half(v.w));
        dst[i] = h;
    }
}

extern "C" void kernel_launch(void* const* d_in, const int* in_sizes, int n_in,
                              void* d_out, int out_size, void* d_ws, size_t ws_size,
                              hipStream_t stream) {
    const float* user_emb   = (const float*)d_in[0];
    const float* entity_emb = (const float*)d_in[1];
    const int*   kg_row     = (const int*)d_in[2];
    const int*   kg_col     = (const int*)d_in[3];
    const float* kg_vals    = (const float*)d_in[4];
    const int*   ui_row     = (const int*)d_in[5];
    const int*   ui_col     = (const int*)d_in[6];
    const float* ui_vals    = (const float*)d_in[7];

    const int n_users    = in_sizes[0] / D;   // 100000
    const int n_entities = in_sizes[1] / D;   // 150000
    const int kg_nnz     = in_sizes[2];       // 2.4M
    const int ui_nnz     = in_sizes[5];       // 3.2M
    const int n_ui       = n_entities;        // 150000 = n_users + n_items here

    // ---- ws layout ----
    __half* A = (__half*)d_ws;                     // n_ui*64 halfs (19.2 MB)
    __half* B = A + (long)n_ui * D;                // n_ui*64 halfs
    int*   kg_cnt  = (int*)(B + (long)n_ui * D);   // n_entities (hist, then cursor)
    int*   kg_rp   = kg_cnt + n_entities;          // n_entities+1
    int*   kg_cs   = kg_rp + n_entities + 1;       // kg_nnz
    float* kg_vs   = (float*)(kg_cs + kg_nnz);     // kg_nnz
    int*   ui_cnt  = (int*)(kg_vs + kg_nnz);       // n_ui (hist, then cursor)
    int*   ui_rp   = ui_cnt + n_ui;                // n_ui+1
    int*   ui_cs   = ui_rp + n_ui + 1;             // ui_nnz
    float* ui_vs   = (float*)(ui_cs + ui_nnz);     // ui_nnz
    int*   tsum    = (int*)(ui_vs + ui_nnz);       // SCAN_THREADS

    float* dout_user = (float*)d_out;                  // 6.4M floats
    float* dout_ent  = dout_user + (long)n_users * D;  // 9.6M floats

    const int BLK = 256;
    auto cdiv = [](long a, long b) { return (int)((a + b - 1) / b); };

    // ---- build CSR: KG ----
    zero_kernel<<<cdiv(n_entities, BLK), BLK, 0, stream>>>(kg_cnt, n_entities);
    hist_kernel<<<cdiv(kg_nnz, BLK), BLK, 0, stream>>>(kg_row, kg_cnt, kg_nnz);
    scan_s1_kernel<<<SCAN_BLOCKS, SCAN_BT, 0, stream>>>(kg_cnt, tsum, n_entities);
    scan_s2_kernel<<<1, 1024, 0, stream>>>(tsum);
    scan_s3_kernel<<<SCAN_BLOCKS, SCAN_BT, 0, stream>>>(kg_cnt, tsum, kg_rp, n_entities);
    scatter_kernel<<<cdiv(kg_nnz, BLK), BLK, 0, stream>>>(kg_row, kg_col, kg_vals,
                                                          kg_cnt, kg_cs, kg_vs, kg_nnz);
    // ---- build CSR: UI ----
    zero_kernel<<<cdiv(n_ui, BLK), BLK, 0, stream>>>(ui_cnt, n_ui);
    hist_kernel<<<cdiv(ui_nnz, BLK), BLK, 0, stream>>>(ui_row, ui_cnt, ui_nnz);
    scan_s1_kernel<<<SCAN_BLOCKS, SCAN_BT, 0, stream>>>(ui_cnt, tsum, n_ui);
    scan_s2_kernel<<<1, 1024, 0, stream>>>(tsum);
    scan_s3_kernel<<<SCAN_BLOCKS, SCAN_BT, 0, stream>>>(ui_cnt, tsum, ui_rp, n_ui);
    scatter_kernel<<<cdiv(ui_nnz, BLK), BLK, 0, stream>>>(ui_row, ui_col, ui_vals,
                                                          ui_cnt, ui_cs, ui_vs, ui_nnz);

    // ---- entity (KG) phase: 2 layers ----
    // l1: A(half) = S·emb ; dout_ent = emb + S·emb
    spmm_csr_kernel<float><<<cdiv((long)n_entities * 64, BLK), BLK, 0, stream>>>(
        kg_rp, kg_cs, kg_vs, entity_emb, A, dout_ent, n_entities, n_entities, 1, 0.f);
    // l2: dout_ent = (dout_ent + S·A) / 3
    spmm_csr_kernel<__half><<<cdiv((long)n_entities * 64, BLK), BLK, 0, stream>>>(
        kg_rp, kg_cs, kg_vs, A, (__half*)nullptr, dout_ent, n_entities, n_entities, 3, 1.f / 3.f);

    // ---- UI phase: 3 layers ----
    // B(half) = concat(user_emb, entity_out[:n_items])
    concat_half_kernel<<<cdiv((long)n_ui * (D / 4), BLK), BLK, 0, stream>>>(
        (const float4*)user_emb, (const float4*)dout_ent, (ushort4*)B,
        (long)n_users * (D / 4), (long)n_ui * (D / 4));
    // l1: A = S·B ; dout_user = B[:U] + S·B[:U]
    spmm_csr_kernel<__half><<<cdiv((long)n_ui * 64, BLK), BLK, 0, stream>>>(
        ui_rp, ui_cs, ui_vs, B, A, dout_user, n_ui, n_users, 1, 0.f);
    // l2: B = S·A ; dout_user += (S·A)[:U]
    spmm_csr_kernel<__half><<<cdiv((long)n_ui * 64, BLK), BLK, 0, stream>>>(
        ui_rp, ui_cs, ui_vs, A, B, dout_user, n_ui, n_users, 2, 0.f);
    // l3 (user rows only): dout_user = (dout_user + S·B) / 4
    spmm_csr_kernel<__half><<<cdiv((long)n_users * 64, BLK), BLK, 0, stream>>>(
        ui_rp, ui_cs, ui_vs, B, (__half*)nullptr, dout_user, n_users, n_users, 3, 0.25f);
}

// Round 11
// 1381.691 us; speedup vs baseline: 8.9415x; 1.0096x over previous
//
#include <hip/hip_runtime.h>
#include <hip/hip_fp16.h>

// KGCN-style propagation, PULL-based CSR (interleaved int2 edge records),
// fp16 inter-layer tables, hierarchical parallel scan.
//   entity_out = (emb + S_kg·emb + S_kg²·emb) / 3          [150000 x 64]
//   ui_emb     = concat(user_emb, entity_out[:50000])      [150000 x 64]
//   user_out   = (Σ_{k=0..3} S_ui^k·ui_emb)[:100000] / 4   [100000 x 64]
// d_out = [user_out (6.4M f32) | entity_out (9.6M f32)]

constexpr int D = 64;
constexpr int SCAN_BLOCKS = 32;
constexpr int SCAN_BT = 256;
constexpr int SCAN_THREADS = SCAN_BLOCKS * SCAN_BT;   // 8192

// ---------------- CSR build (counting sort) ----------------

__global__ void zero_kernel(int* __restrict__ p, int n) {
    int i = blockIdx.x * blockDim.x + threadIdx.x;
    if (i < n) p[i] = 0;
}

__global__ void hist_kernel(const int* __restrict__ row, int* __restrict__ cnt, int nnz) {
    int i = blockIdx.x * blockDim.x + threadIdx.x;
    if (i < nnz) atomicAdd(&cnt[row[i]], 1);
}

// S1: thread t sums its chunk of cnt -> tsum[t]
__global__ void scan_s1_kernel(const int* __restrict__ cnt, int* __restrict__ tsum, int n) {
    int t = blockIdx.x * blockDim.x + threadIdx.x;
    int chunk = (n + SCAN_THREADS - 1) / SCAN_THREADS;
    int lo = t * chunk;
    int hi = min(lo + chunk, n);
    int s = 0;
    for (int i = lo; i < hi; ++i) s += cnt[i];
    tsum[t] = s;
}

// S2: single block, exclusive scan of tsum[SCAN_THREADS] in place (each thread owns 8)
__global__ void scan_s2_kernel(int* __restrict__ tsum) {
    __shared__ int lds[1024];
    int tid = threadIdx.x;                     // 1024 threads
    const int PER = SCAN_THREADS / 1024;       // 8
    int v[PER];
    int s = 0;
    for (int j = 0; j < PER; ++j) { v[j] = tsum[tid * PER + j]; s += v[j]; }
    lds[tid] = s;
    __syncthreads();
    for (int ofs = 1; ofs < 1024; ofs <<= 1) {
        int x = (tid >= ofs) ? lds[tid - ofs] : 0;
        __syncthreads();
        lds[tid] += x;
        __syncthreads();
    }
    int run = (tid > 0) ? lds[tid - 1] : 0;
    for (int j = 0; j < PER; ++j) { int c = v[j]; tsum[tid * PER + j] = run; run += c; }
}

// S3: thread t re-reads its chunk, emits rp[] and cursor (cnt in place)
__global__ void scan_s3_kernel(int* __restrict__ cnt, const int* __restrict__ tsum,
                               int* __restrict__ rp, int n) {
    int t = blockIdx.x * blockDim.x + threadIdx.x;
    int chunk = (n + SCAN_THREADS - 1) / SCAN_THREADS;
    int lo = t * chunk;
    int hi = min(lo + chunk, n);
    int run = tsum[t];
    for (int i = lo; i < hi; ++i) {
        int c = cnt[i];
        rp[i] = run;
        cnt[i] = run;   // becomes the scatter cursor
        run += c;
    }
    if (hi == n && lo <= n) rp[n] = run;   // last chunk writes total
}

// scatter edge records: one int2 (col, val-bits) per edge -> single random 8B write
__global__ void scatter_kernel(const int* __restrict__ row, const int* __restrict__ col,
                               const float* __restrict__ val, int* __restrict__ cursor,
                               int2* __restrict__ ev, int nnz) {
    int i = blockIdx.x * blockDim.x + threadIdx.x;
    if (i < nnz) {
        int p = atomicAdd(&cursor[row[i]], 1);
        ev[p] = make_int2(col[i], __float_as_int(val[i]));
    }
}

// ---------------- pull SpMM: one wave per row, lane = dim ----------------
__device__ __forceinline__ float ldval(const float* p) { return *p; }
__device__ __forceinline__ float ldval(const __half* p) { return __half2float(*p); }

// s = Σ_e val(ev[e]) * cur[col(ev[e])*64 + lane]
// if (next)            next[row] = (half)s
// if (row < acc_rows)  mode 1: acc[row] = cur[row] + s
//                      mode 2: acc[row] += s
//                      mode 3: acc[row] = (acc[row]+s)*scale
template <typename TIn>
__global__ void spmm_csr_kernel(const int* __restrict__ rp, const int2* __restrict__ ev,
                                const TIn* __restrict__ cur,
                                __half* __restrict__ next, float* __restrict__ acc,
                                int n_rows, int acc_rows, int mode, float scale) {
    int wid = (int)(((long)blockIdx.x * blockDim.x + threadIdx.x) >> 6);
    int lane = threadIdx.x & 63;
    if (wid >= n_rows) return;
    int start = rp[wid];
    int end = rp[wid + 1];
    float s0 = 0.f, s1 = 0.f, s2 = 0.f, s3 = 0.f;
    int e = start;
    for (; e + 3 < end; e += 4) {
        int2 p0 = ev[e], p1 = ev[e + 1], p2 = ev[e + 2], p3 = ev[e + 3];
        s0 += __int_as_float(p0.y) * ldval(cur + (long)p0.x * D + lane);
        s1 += __int_as_float(p1.y) * ldval(cur + (long)p1.x * D + lane);
        s2 += __int_as_float(p2.y) * ldval(cur + (long)p2.x * D + lane);
        s3 += __int_as_float(p3.y) * ldval(cur + (long)p3.x * D + lane);
    }
    for (; e < end; ++e) {
        int2 p = ev[e];
        s0 += __int_as_float(p.y) * ldval(cur + (long)p.x * D + lane);
    }
    float s = (s0 + s1) + (s2 + s3);
    long o = (long)wid * D + lane;
    if (next) next[o] = __float2half(s);
    if (wid < acc_rows) {
        if (mode == 1)      acc[o] = ldval(cur + o) + s;
        else if (mode == 2) acc[o] += s;
        else if (mode == 3) acc[o] = (acc[o] + s) * scale;
    }
}

// dst(half) = concat(user_emb, entity_out[:n_items])
__global__ void concat_half_kernel(const float4* __restrict__ u, const float4* __restrict__ e,
                                   ushort4* __restrict__ dst, long nU4, long nT4) {
    long i = (long)blockIdx.x * blockDim.x + threadIdx.x;
    if (i < nT4) {
        float4 v = (i < nU4) ? u[i] : e[i - nU4];
        ushort4 h;
        h.x = __half_as_ushort(__float2half(v.x));
        h.y = __half_as_ushort(__float2half(v.y));
        h.z = __half_as_ushort(__float2half(v.z));
        h.w = __half_as_ushort(__float2half(v.w));
        dst[i] = h;
    }
}

extern "C" void kernel_launch(void* const* d_in, const int* in_sizes, int n_in,
                              void* d_out, int out_size, void* d_ws, size_t ws_size,
                              hipStream_t stream) {
    const float* user_emb   = (const float*)d_in[0];
    const float* entity_emb = (const float*)d_in[1];
    const int*   kg_row     = (const int*)d_in[2];
    const int*   kg_col     = (const int*)d_in[3];
    const float* kg_vals    = (const float*)d_in[4];
    const int*   ui_row     = (const int*)d_in[5];
    const int*   ui_col     = (const int*)d_in[6];
    const float* ui_vals    = (const float*)d_in[7];

    const int n_users    = in_sizes[0] / D;   // 100000
    const int n_entities = in_sizes[1] / D;   // 150000
    const int kg_nnz     = in_sizes[2];       // 2.4M
    const int ui_nnz     = in_sizes[5];       // 3.2M
    const int n_ui       = n_entities;        // 150000 = n_users + n_items here

    // ---- ws layout (int2 arrays kept 8B-aligned via +1 pad after rp) ----
    __half* A = (__half*)d_ws;                     // n_ui*64 halfs (19.2 MB)
    __half* B = A + (long)n_ui * D;                // n_ui*64 halfs
    int*   kg_cnt = (int*)(B + (long)n_ui * D);    // n_entities (hist, then cursor)
    int*   kg_rp  = kg_cnt + n_entities;           // n_entities+1 (+1 pad)
    int2*  kg_ev  = (int2*)(kg_rp + n_entities + 2);  // kg_nnz int2
    int*   ui_cnt = (int*)(kg_ev + kg_nnz);        // n_ui
    int*   ui_rp  = ui_cnt + n_ui;                 // n_ui+1 (+1 pad)
    int2*  ui_ev  = (int2*)(ui_rp + n_ui + 2);     // ui_nnz int2
    int*   tsum   = (int*)(ui_ev + ui_nnz);        // SCAN_THREADS

    float* dout_user = (float*)d_out;                  // 6.4M floats
    float* dout_ent  = dout_user + (long)n_users * D;  // 9.6M floats

    const int BLK = 256;
    auto cdiv = [](long a, long b) { return (int)((a + b - 1) / b); };

    // ---- build CSR: KG ----
    zero_kernel<<<cdiv(n_entities, BLK), BLK, 0, stream>>>(kg_cnt, n_entities);
    hist_kernel<<<cdiv(kg_nnz, BLK), BLK, 0, stream>>>(kg_row, kg_cnt, kg_nnz);
    scan_s1_kernel<<<SCAN_BLOCKS, SCAN_BT, 0, stream>>>(kg_cnt, tsum, n_entities);
    scan_s2_kernel<<<1, 1024, 0, stream>>>(tsum);
    scan_s3_kernel<<<SCAN_BLOCKS, SCAN_BT, 0, stream>>>(kg_cnt, tsum, kg_rp, n_entities);
    scatter_kernel<<<cdiv(kg_nnz, BLK), BLK, 0, stream>>>(kg_row, kg_col, kg_vals,
                                                          kg_cnt, kg_ev, kg_nnz);
    // ---- build CSR: UI ----
    zero_kernel<<<cdiv(n_ui, BLK), BLK, 0, stream>>>(ui_cnt, n_ui);
    hist_kernel<<<cdiv(ui_nnz, BLK), BLK, 0, stream>>>(ui_row, ui_cnt, ui_nnz);
    scan_s1_kernel<<<SCAN_BLOCKS, SCAN_BT, 0, stream>>>(ui_cnt, tsum, n_ui);
    scan_s2_kernel<<<1, 1024, 0, stream>>>(tsum);
    scan_s3_kernel<<<SCAN_BLOCKS, SCAN_BT, 0, stream>>>(ui_cnt, tsum, ui_rp, n_ui);
    scatter_kernel<<<cdiv(ui_nnz, BLK), BLK, 0, stream>>>(ui_row, ui_col, ui_vals,
                                                          ui_cnt, ui_ev, ui_nnz);

    // ---- entity (KG) phase: 2 layers ----
    // l1: A(half) = S·emb ; dout_ent = emb + S·emb
    spmm_csr_kernel<float><<<cdiv((long)n_entities * 64, BLK), BLK, 0, stream>>>(
        kg_rp, kg_ev, entity_emb, A, dout_ent, n_entities, n_entities, 1, 0.f);
    // l2: dout_ent = (dout_ent + S·A) / 3
    spmm_csr_kernel<__half><<<cdiv((long)n_entities * 64, BLK), BLK, 0, stream>>>(
        kg_rp, kg_ev, A, (__half*)nullptr, dout_ent, n_entities, n_entities, 3, 1.f / 3.f);

    // ---- UI phase: 3 layers ----
    // B(half) = concat(user_emb, entity_out[:n_items])
    concat_half_kernel<<<cdiv((long)n_ui * (D / 4), BLK), BLK, 0, stream>>>(
        (const float4*)user_emb, (const float4*)dout_ent, (ushort4*)B,
        (long)n_users * (D / 4), (long)n_ui * (D / 4));
    // l1: A = S·B ; dout_user = B[:U] + S·B[:U]
    spmm_csr_kernel<__half><<<cdiv((long)n_ui * 64, BLK), BLK, 0, stream>>>(
        ui_rp, ui_ev, B, A, dout_user, n_ui, n_users, 1, 0.f);
    // l2: B = S·A ; dout_user += (S·A)[:U]
    spmm_csr_kernel<__half><<<cdiv((long)n_ui * 64, BLK), BLK, 0, stream>>>(
        ui_rp, ui_ev, A, B, dout_user, n_ui, n_users, 2, 0.f);
    // l3 (user rows only): dout_user = (dout_user + S·B) / 4
    spmm_csr_kernel<__half><<<cdiv((long)n_users * 64, BLK), BLK, 0, stream>>>(
        ui_rp, ui_ev, B, (__half*)nullptr, dout_user, n_users, n_users, 3, 0.25f);
}